// Round 4
// baseline (239.673 us; speedup 1.0000x reference)
//
#include <hip/hip_runtime.h>
#include <hip/hip_bf16.h>
#include <math.h>

#define S_LEN 8192
#define DK    128
#define BM    128               // q rows per block (8 waves x 16)
#define BN    64                // keys per tile
#define NQT   (S_LEN / BM)      // 64 query tiles
#define NW    8
#define SCALE 0.08838834764831845f   // 1/sqrt(128)

typedef __bf16 bf16x8_t __attribute__((ext_vector_type(8)));
typedef __bf16 bf16x4_t __attribute__((ext_vector_type(4)));
typedef __bf16 bf16x2_t __attribute__((ext_vector_type(2)));
typedef float  floatx4  __attribute__((ext_vector_type(4)));

// async global->LDS, 16 B per lane; LDS dst = wave-uniform base + lane*16
#define GLD16(g, l) __builtin_amdgcn_global_load_lds(                      \
    (const __attribute__((address_space(1))) void*)(g),                    \
    (__attribute__((address_space(3))) void*)(l), 16, 0, 0)

// ---- fused one-time prep: Q,K -> bf16 row-major; V -> bf16 transposed ----
__global__ __launch_bounds__(256)
void prep(const float* __restrict__ Q, const float* __restrict__ K,
          const float* __restrict__ V, __bf16* __restrict__ Qb,
          __bf16* __restrict__ Kb, __bf16* __restrict__ Vt) {
  const int b = blockIdx.x;
  __shared__ __bf16 t[64][DK + 8];
  if (b < 2048) {
    const float* src = (b < 1024) ? Q : K;
    __bf16* dst = (b < 1024) ? Qb : Kb;
    const int i = ((b & 1023) * 256 + threadIdx.x) * 4;
    float4 v = *(const float4*)&src[i];
    bf16x4_t o;
    o[0] = (__bf16)v.x; o[1] = (__bf16)v.y; o[2] = (__bf16)v.z; o[3] = (__bf16)v.w;
    *(bf16x4_t*)&dst[i] = o;
  } else {
    const int tid  = threadIdx.x;
    const int key0 = (b - 2048) * 64;
    {
      const int r = tid >> 2, cg = (tid & 3) * 32;
      const float* vp = V + (size_t)(key0 + r) * DK + cg;
      #pragma unroll
      for (int i = 0; i < 8; ++i) {
        float4 v = ((const float4*)vp)[i];
        bf16x4_t o;
        o[0]=(__bf16)v.x; o[1]=(__bf16)v.y; o[2]=(__bf16)v.z; o[3]=(__bf16)v.w;
        *(bf16x4_t*)&t[r][cg + i * 4] = o;
      }
    }
    __syncthreads();
    const int d = tid >> 1, h = (tid & 1) * 32;
    __bf16* op = Vt + (size_t)d * S_LEN + key0 + h;
    #pragma unroll
    for (int jb = 0; jb < 4; ++jb) {
      bf16x8_t o;
      #pragma unroll
      for (int j = 0; j < 8; ++j) o[j] = t[h + jb * 8 + j][d];
      *(bf16x8_t*)&op[jb * 8] = o;
    }
  }
}

// ---- flash attention partial, split-K, 8 waves x 16 q-rows ----
// Ks: 64 keys x 128 d bf16, 16B-chunk XOR swizzle: phys = c ^ (row&15)
// Vts: 128 d x 64 keys bf16, swizzle: phys = c ^ (row&7)
__global__ __launch_bounds__(512, 6)
void fa_part(const __bf16* __restrict__ Qb, const __bf16* __restrict__ Kb,
             const __bf16* __restrict__ Vtg, __bf16* __restrict__ Opart,
             float* __restrict__ Odirect, float* __restrict__ stats,
             int G, int direct) {
  __shared__ __align__(16) __bf16 Ks[BN * DK];         // 16 KB
  __shared__ __align__(16) __bf16 Vts[DK * BN];        // 16 KB
  __shared__ __align__(16) __bf16 Pl[NW][16][BN + 8];  // 18.4 KB

  const int tid  = threadIdx.x;
  const int wave = tid >> 6;
  const int lane = tid & 63;
  const int l15  = lane & 15;
  const int quad = lane >> 4;

  const int qtile = blockIdx.x;
  const int g     = blockIdx.y;
  const int nt    = 2 * qtile + 2;              // key tiles incl. diagonal
  const int Ci    = (nt + G - 1) / G;
  const int jb0   = g * Ci;
  const int jb1   = (jb0 + Ci < nt) ? (jb0 + Ci) : nt;
  const int chunk = qtile * G + g;

  if (jb0 >= jb1) {
    if (tid < BM) {
      stats[((size_t)chunk * BM + tid) * 2 + 0] = -INFINITY;
      stats[((size_t)chunk * BM + tid) * 2 + 1] = 0.f;
    }
    return;
  }

  const int q0w = qtile * BM + wave * 16;       // first q row of this wave

  // Q fragments (A-layout), bf16 direct load
  bf16x8_t qf[4];
  #pragma unroll
  for (int kb = 0; kb < 4; ++kb)
    qf[kb] = *(const bf16x8_t*)&Qb[(size_t)(q0w + l15) * DK + kb * 32 + quad * 8];

  // staging: wave w fills 1KB segments {2w, 2w+1} of Ks and of Vts
  const __bf16* kp[2]; const __bf16* vp[2];
  const __bf16* kl[2]; const __bf16* vl[2];
  #pragma unroll
  for (int t = 0; t < 2; ++t) {
    const int s  = wave * 2 + t;
    const int rk = 4 * s + (lane >> 4);                 // key row 0..63
    const int ck = (lane & 15) ^ (rk & 15);
    kp[t] = Kb + ((size_t)jb0 * BN + rk) * DK + ck * 8;
    kl[t] = Ks + s * 512;
    const int rv = 8 * s + (lane >> 3);                 // d row 0..127
    const int cv = (lane & 7) ^ (rv & 7);
    vp[t] = Vtg + (size_t)rv * S_LEN + jb0 * BN + cv * 8;
    vl[t] = Vts + s * 512;
  }

  floatx4 o_acc[8];
  #pragma unroll
  for (int dt = 0; dt < 8; ++dt) o_acc[dt] = (floatx4){0.f, 0.f, 0.f, 0.f};
  float m_r[4], l_r[4];
  #pragma unroll
  for (int r = 0; r < 4; ++r) { m_r[r] = -INFINITY; l_r[r] = 0.f; }

  for (int jb = jb0; jb < jb1; ++jb) {
    const int key0 = jb * BN;

    #pragma unroll
    for (int t = 0; t < 2; ++t) {
      GLD16(kp[t], kl[t]);
      GLD16(vp[t], vl[t]);
      kp[t] += BN * DK;
      vp[t] += BN;
    }
    __syncthreads();

    // wave-uniform skip of fully-masked tiles (q0w, key0 both mult of 16,
    // so key0 > q0w+15 <=> every (key,qi) pair in this wave is masked)
    if (key0 <= q0w + 15) {
      // ---- S = Q K^T ----
      floatx4 sv[4];
      #pragma unroll
      for (int n = 0; n < 4; ++n) {
        floatx4 acc = (floatx4){0.f, 0.f, 0.f, 0.f};
        #pragma unroll
        for (int kb = 0; kb < 4; ++kb) {
          bf16x8_t bfr = *(const bf16x8_t*)
              &Ks[(n * 16 + l15) * DK + (((kb * 4 + quad) ^ l15) * 8)];
          acc = __builtin_amdgcn_mfma_f32_16x16x32_bf16(qf[kb], bfr, acc, 0, 0, 0);
        }
        sv[n] = acc;
      }

      // ---- scale (+ causal mask when tile straddles this wave's rows) ----
      if (key0 + BN - 1 > q0w) {
        #pragma unroll
        for (int n = 0; n < 4; ++n) {
          const int key = key0 + n * 16 + l15;
          #pragma unroll
          for (int r = 0; r < 4; ++r) {
            const int qi = q0w + quad * 4 + r;
            float v = sv[n][r] * SCALE;
            sv[n][r] = (key > qi) ? -1e30f : v;
          }
        }
      } else {
        #pragma unroll
        for (int n = 0; n < 4; ++n)
          #pragma unroll
          for (int r = 0; r < 4; ++r) sv[n][r] *= SCALE;
      }

      // ---- online softmax ----
      float rm[4];
      #pragma unroll
      for (int r = 0; r < 4; ++r)
        rm[r] = fmaxf(fmaxf(sv[0][r], sv[1][r]), fmaxf(sv[2][r], sv[3][r]));
      #pragma unroll
      for (int off = 8; off >= 1; off >>= 1) {
        #pragma unroll
        for (int r = 0; r < 4; ++r) rm[r] = fmaxf(rm[r], __shfl_xor(rm[r], off));
      }
      float alpha[4];
      #pragma unroll
      for (int r = 0; r < 4; ++r) {
        const float mn = fmaxf(m_r[r], rm[r]);
        alpha[r] = __expf(m_r[r] - mn);
        m_r[r] = mn;
      }
      float rs[4] = {0.f, 0.f, 0.f, 0.f};
      #pragma unroll
      for (int n = 0; n < 4; ++n) {
        #pragma unroll
        for (int r = 0; r < 4; ++r) {
          const float p = __expf(sv[n][r] - m_r[r]);
          sv[n][r] = p;
          rs[r] += p;
        }
      }
      #pragma unroll
      for (int off = 8; off >= 1; off >>= 1) {
        #pragma unroll
        for (int r = 0; r < 4; ++r) rs[r] += __shfl_xor(rs[r], off);
      }
      #pragma unroll
      for (int r = 0; r < 4; ++r) l_r[r] = l_r[r] * alpha[r] + rs[r];
      #pragma unroll
      for (int dt = 0; dt < 8; ++dt)
        #pragma unroll
        for (int r = 0; r < 4; ++r) o_acc[dt][r] *= alpha[r];

      // ---- P: C-layout -> per-wave LDS -> A-layout (no barrier needed:
      // Pl[wave] is wave-private; lgkmcnt orders intra-wave LDS ops) ----
      #pragma unroll
      for (int n = 0; n < 4; ++n)
        #pragma unroll
        for (int r = 0; r < 4; ++r)
          Pl[wave][quad * 4 + r][n * 16 + l15] = (__bf16)sv[n][r];

      // ---- O += P V ----
      #pragma unroll
      for (int kc = 0; kc < 2; ++kc) {
        bf16x8_t af = *(const bf16x8_t*)&Pl[wave][l15][kc * 32 + quad * 8];
        #pragma unroll
        for (int dt = 0; dt < 8; ++dt) {
          bf16x8_t vf = *(const bf16x8_t*)
              &Vts[(dt * 16 + l15) * BN + (((kc * 4 + quad) ^ (l15 & 7)) * 8)];
          o_acc[dt] = __builtin_amdgcn_mfma_f32_16x16x32_bf16(af, vf, o_acc[dt], 0, 0, 0);
        }
      }
    }
    __syncthreads();
  }

  // ---- epilogue ----
  if (direct) {
    #pragma unroll
    for (int r = 0; r < 4; ++r) {
      const float inv = 1.0f / l_r[r];
      float* orow = Odirect + (size_t)(q0w + quad * 4 + r) * DK + l15;
      #pragma unroll
      for (int dt = 0; dt < 8; ++dt) orow[dt * 16] = o_acc[dt][r] * inv;
    }
  } else {
    #pragma unroll
    for (int r = 0; r < 4; ++r) {
      const int row = wave * 16 + quad * 4 + r;
      __bf16* orow = Opart + ((size_t)chunk * BM + row) * DK + l15;
      #pragma unroll
      for (int dt = 0; dt < 8; ++dt) orow[dt * 16] = (__bf16)o_acc[dt][r];
    }
    if (l15 == 0) {
      #pragma unroll
      for (int r = 0; r < 4; ++r) {
        const int row = wave * 16 + quad * 4 + r;
        stats[((size_t)chunk * BM + row) * 2 + 0] = m_r[r];
        stats[((size_t)chunk * BM + row) * 2 + 1] = l_r[r];
      }
    }
  }
}

// ---- combine: wave per query row, lane covers 2 columns (bf16 partials) ----
__global__ __launch_bounds__(256)
void fa_reduce(const __bf16* __restrict__ Opart, const float* __restrict__ stats,
               float* __restrict__ O, int G) {
  const int wave = threadIdx.x >> 6, lane = threadIdx.x & 63;
  const int row = blockIdx.x * 4 + wave;
  const int qt = row >> 7, r = row & 127;

  float M = -INFINITY;
  for (int g = 0; g < G; ++g)
    M = fmaxf(M, stats[((size_t)(qt * G + g) * BM + r) * 2]);

  float L = 0.f, ax = 0.f, ay = 0.f;
  for (int g = 0; g < G; ++g) {
    const size_t sidx = (size_t)(qt * G + g) * BM + r;
    const float m = stats[sidx * 2];
    if (m == -INFINITY) continue;
    const float w = __expf(m - M);
    L += stats[sidx * 2 + 1] * w;
    bf16x2_t o = *(const bf16x2_t*)&Opart[sidx * DK + lane * 2];
    ax += w * (float)o[0];
    ay += w * (float)o[1];
  }
  const float inv = 1.f / L;
  float2 res; res.x = ax * inv; res.y = ay * inv;
  *(float2*)&O[(size_t)row * DK + lane * 2] = res;
}

extern "C" void kernel_launch(void* const* d_in, const int* in_sizes, int n_in,
                              void* d_out, int out_size, void* d_ws, size_t ws_size,
                              hipStream_t stream) {
  (void)in_sizes; (void)n_in; (void)out_size;
  const float* q = (const float*)d_in[0];
  const float* k = (const float*)d_in[1];
  const float* v = (const float*)d_in[2];
  float* out = (float*)d_out;

  const size_t conv = 3 * (size_t)S_LEN * DK * 2;                       // 6 MB
  const size_t per_g = (size_t)NQT * BM * DK * 2                        // bf16 Opart
                     + (size_t)NQT * BM * 2 * sizeof(float);            // stats
  int G = 1;
  if (ws_size > conv + 2 * per_g) {
    G = (int)((ws_size - conv) / per_g);
    if (G > 8) G = 8;
  }

  __bf16* Qb = (__bf16*)d_ws;
  __bf16* Kb = Qb + (size_t)S_LEN * DK;
  __bf16* Vt = Kb + (size_t)S_LEN * DK;
  __bf16* Opart = Vt + (size_t)S_LEN * DK;
  float* stats = (float*)(Opart + (size_t)NQT * G * BM * DK);

  prep<<<2176, 256, 0, stream>>>(q, k, v, Qb, Kb, Vt);

  if (G >= 2) {
    fa_part<<<dim3(NQT, G), 512, 0, stream>>>(Qb, Kb, Vt, Opart, nullptr, stats, G, 0);
    fa_reduce<<<S_LEN / 4, 256, 0, stream>>>(Opart, stats, out, G);
  } else {
    fa_part<<<dim3(NQT, 1), 512, 0, stream>>>(Qb, Kb, Vt, Opart, out, stats, 1, 1);
  }
}

// Round 5
// 141.629 us; speedup vs baseline: 1.6923x; 1.6923x over previous
//
#include <hip/hip_runtime.h>
#include <hip/hip_bf16.h>
#include <math.h>

#define S_LEN 8192
#define DK    128
#define BM    128               // q rows per block (8 waves x 16)
#define BN    64                // keys per tile
#define NQT   (S_LEN / BM)      // 64 query tiles
#define NW    8
#define SCALE 0.08838834764831845f   // 1/sqrt(128)

typedef __bf16 bf16x8_t __attribute__((ext_vector_type(8)));
typedef __bf16 bf16x4_t __attribute__((ext_vector_type(4)));
typedef __bf16 bf16x2_t __attribute__((ext_vector_type(2)));
typedef float  floatx4  __attribute__((ext_vector_type(4)));

// async global->LDS, 16 B per lane; LDS dst = wave-uniform base + lane*16
#define GLD16(g, l) __builtin_amdgcn_global_load_lds(                      \
    (const __attribute__((address_space(1))) void*)(g),                    \
    (__attribute__((address_space(3))) void*)(l), 16, 0, 0)

// ---- fused one-time prep: Q,K -> bf16 row-major; V -> bf16 transposed ----
__global__ __launch_bounds__(256)
void prep(const float* __restrict__ Q, const float* __restrict__ K,
          const float* __restrict__ V, __bf16* __restrict__ Qb,
          __bf16* __restrict__ Kb, __bf16* __restrict__ Vt) {
  const int b = blockIdx.x;
  __shared__ __bf16 t[64][DK + 8];
  if (b < 2048) {
    const float* src = (b < 1024) ? Q : K;
    __bf16* dst = (b < 1024) ? Qb : Kb;
    const int i = ((b & 1023) * 256 + threadIdx.x) * 4;
    float4 v = *(const float4*)&src[i];
    bf16x4_t o;
    o[0] = (__bf16)v.x; o[1] = (__bf16)v.y; o[2] = (__bf16)v.z; o[3] = (__bf16)v.w;
    *(bf16x4_t*)&dst[i] = o;
  } else {
    const int tid  = threadIdx.x;
    const int key0 = (b - 2048) * 64;
    {
      const int r = tid >> 2, cg = (tid & 3) * 32;
      const float* vp = V + (size_t)(key0 + r) * DK + cg;
      #pragma unroll
      for (int i = 0; i < 8; ++i) {
        float4 v = ((const float4*)vp)[i];
        bf16x4_t o;
        o[0]=(__bf16)v.x; o[1]=(__bf16)v.y; o[2]=(__bf16)v.z; o[3]=(__bf16)v.w;
        *(bf16x4_t*)&t[r][cg + i * 4] = o;
      }
    }
    __syncthreads();
    const int d = tid >> 1, h = (tid & 1) * 32;
    __bf16* op = Vt + (size_t)d * S_LEN + key0 + h;
    #pragma unroll
    for (int jb = 0; jb < 4; ++jb) {
      bf16x8_t o;
      #pragma unroll
      for (int j = 0; j < 8; ++j) o[j] = t[h + jb * 8 + j][d];
      *(bf16x8_t*)&op[jb * 8] = o;
    }
  }
}

// ---- flash attention partial, split-K, 8 waves x 16 q-rows ----
// Ks: 64 keys x 128 d bf16, 16B-chunk XOR swizzle: phys = c ^ (row&15)
// Vts: 128 d x 64 keys bf16, swizzle: phys = c ^ (row&7)
// launch_bounds (512,4): VGPR cap 128 -> compiler's natural ~76, NO SPILL.
// (512,6) in round 4 capped at ~85 incl. unified AGPRs -> spilled o_acc,
// 165 MB scratch writes/dispatch. Do not raise the 2nd arg.
__global__ __launch_bounds__(512, 4)
void fa_part(const __bf16* __restrict__ Qb, const __bf16* __restrict__ Kb,
             const __bf16* __restrict__ Vtg, __bf16* __restrict__ Opart,
             float* __restrict__ Odirect, float* __restrict__ stats,
             int G, int direct) {
  __shared__ __align__(16) __bf16 Ks[BN * DK];         // 16 KB
  __shared__ __align__(16) __bf16 Vts[DK * BN];        // 16 KB
  __shared__ __align__(16) __bf16 Pl[NW][16][BN + 8];  // 18.4 KB

  const int tid  = threadIdx.x;
  const int wave = tid >> 6;
  const int lane = tid & 63;
  const int l15  = lane & 15;
  const int quad = lane >> 4;

  const int qtile = blockIdx.x;
  const int g     = blockIdx.y;
  const int nt    = 2 * qtile + 2;              // key tiles incl. diagonal
  const int Ci    = (nt + G - 1) / G;
  const int jb0   = g * Ci;
  const int jb1   = (jb0 + Ci < nt) ? (jb0 + Ci) : nt;
  const int chunk = qtile * G + g;

  if (jb0 >= jb1) {
    if (tid < BM) {
      stats[((size_t)chunk * BM + tid) * 2 + 0] = -INFINITY;
      stats[((size_t)chunk * BM + tid) * 2 + 1] = 0.f;
    }
    return;
  }

  const int q0w = qtile * BM + wave * 16;       // first q row of this wave

  // Q fragments (A-layout), bf16 direct load
  bf16x8_t qf[4];
  #pragma unroll
  for (int kb = 0; kb < 4; ++kb)
    qf[kb] = *(const bf16x8_t*)&Qb[(size_t)(q0w + l15) * DK + kb * 32 + quad * 8];

  // staging: wave w fills 1KB segments {2w, 2w+1} of Ks and of Vts
  const __bf16* kp[2]; const __bf16* vp[2];
  const __bf16* kl[2]; const __bf16* vl[2];
  #pragma unroll
  for (int t = 0; t < 2; ++t) {
    const int s  = wave * 2 + t;
    const int rk = 4 * s + (lane >> 4);                 // key row 0..63
    const int ck = (lane & 15) ^ (rk & 15);
    kp[t] = Kb + ((size_t)jb0 * BN + rk) * DK + ck * 8;
    kl[t] = Ks + s * 512;
    const int rv = 8 * s + (lane >> 3);                 // d row 0..127
    const int cv = (lane & 7) ^ (rv & 7);
    vp[t] = Vtg + (size_t)rv * S_LEN + jb0 * BN + cv * 8;
    vl[t] = Vts + s * 512;
  }

  floatx4 o_acc[8];
  #pragma unroll
  for (int dt = 0; dt < 8; ++dt) o_acc[dt] = (floatx4){0.f, 0.f, 0.f, 0.f};
  float m_r[4], l_r[4];
  #pragma unroll
  for (int r = 0; r < 4; ++r) { m_r[r] = -INFINITY; l_r[r] = 0.f; }

  for (int jb = jb0; jb < jb1; ++jb) {
    const int key0 = jb * BN;

    #pragma unroll
    for (int t = 0; t < 2; ++t) {
      GLD16(kp[t], kl[t]);
      GLD16(vp[t], vl[t]);
      kp[t] += BN * DK;
      vp[t] += BN;
    }
    __syncthreads();

    // wave-uniform skip of fully-masked tiles (q0w, key0 both mult of 16,
    // so key0 > q0w+15 <=> every (key,qi) pair in this wave is masked)
    if (key0 <= q0w + 15) {
      // ---- S = Q K^T ----
      floatx4 sv[4];
      #pragma unroll
      for (int n = 0; n < 4; ++n) {
        floatx4 acc = (floatx4){0.f, 0.f, 0.f, 0.f};
        #pragma unroll
        for (int kb = 0; kb < 4; ++kb) {
          bf16x8_t bfr = *(const bf16x8_t*)
              &Ks[(n * 16 + l15) * DK + (((kb * 4 + quad) ^ l15) * 8)];
          acc = __builtin_amdgcn_mfma_f32_16x16x32_bf16(qf[kb], bfr, acc, 0, 0, 0);
        }
        sv[n] = acc;
      }

      // ---- scale (+ causal mask when tile straddles this wave's rows) ----
      if (key0 + BN - 1 > q0w) {
        #pragma unroll
        for (int n = 0; n < 4; ++n) {
          const int key = key0 + n * 16 + l15;
          #pragma unroll
          for (int r = 0; r < 4; ++r) {
            const int qi = q0w + quad * 4 + r;
            float v = sv[n][r] * SCALE;
            sv[n][r] = (key > qi) ? -1e30f : v;
          }
        }
      } else {
        #pragma unroll
        for (int n = 0; n < 4; ++n)
          #pragma unroll
          for (int r = 0; r < 4; ++r) sv[n][r] *= SCALE;
      }

      // ---- online softmax ----
      float rm[4];
      #pragma unroll
      for (int r = 0; r < 4; ++r)
        rm[r] = fmaxf(fmaxf(sv[0][r], sv[1][r]), fmaxf(sv[2][r], sv[3][r]));
      #pragma unroll
      for (int off = 8; off >= 1; off >>= 1) {
        #pragma unroll
        for (int r = 0; r < 4; ++r) rm[r] = fmaxf(rm[r], __shfl_xor(rm[r], off));
      }
      float alpha[4];
      #pragma unroll
      for (int r = 0; r < 4; ++r) {
        const float mn = fmaxf(m_r[r], rm[r]);
        alpha[r] = __expf(m_r[r] - mn);
        m_r[r] = mn;
      }
      float rs[4] = {0.f, 0.f, 0.f, 0.f};
      #pragma unroll
      for (int n = 0; n < 4; ++n) {
        #pragma unroll
        for (int r = 0; r < 4; ++r) {
          const float p = __expf(sv[n][r] - m_r[r]);
          sv[n][r] = p;
          rs[r] += p;
        }
      }
      #pragma unroll
      for (int off = 8; off >= 1; off >>= 1) {
        #pragma unroll
        for (int r = 0; r < 4; ++r) rs[r] += __shfl_xor(rs[r], off);
      }
      #pragma unroll
      for (int r = 0; r < 4; ++r) l_r[r] = l_r[r] * alpha[r] + rs[r];
      #pragma unroll
      for (int dt = 0; dt < 8; ++dt)
        #pragma unroll
        for (int r = 0; r < 4; ++r) o_acc[dt][r] *= alpha[r];

      // ---- P: C-layout -> per-wave LDS -> A-layout (wave-private; no
      // barrier needed, lgkmcnt orders intra-wave LDS ops) ----
      #pragma unroll
      for (int n = 0; n < 4; ++n)
        #pragma unroll
        for (int r = 0; r < 4; ++r)
          Pl[wave][quad * 4 + r][n * 16 + l15] = (__bf16)sv[n][r];

      // ---- O += P V ----
      #pragma unroll
      for (int kc = 0; kc < 2; ++kc) {
        bf16x8_t af = *(const bf16x8_t*)&Pl[wave][l15][kc * 32 + quad * 8];
        #pragma unroll
        for (int dt = 0; dt < 8; ++dt) {
          bf16x8_t vf = *(const bf16x8_t*)
              &Vts[(dt * 16 + l15) * BN + (((kc * 4 + quad) ^ (l15 & 7)) * 8)];
          o_acc[dt] = __builtin_amdgcn_mfma_f32_16x16x32_bf16(af, vf, o_acc[dt], 0, 0, 0);
        }
      }
    }
    __syncthreads();
  }

  // ---- epilogue ----
  if (direct) {
    #pragma unroll
    for (int r = 0; r < 4; ++r) {
      const float inv = 1.0f / l_r[r];
      float* orow = Odirect + (size_t)(q0w + quad * 4 + r) * DK + l15;
      #pragma unroll
      for (int dt = 0; dt < 8; ++dt) orow[dt * 16] = o_acc[dt][r] * inv;
    }
  } else {
    #pragma unroll
    for (int r = 0; r < 4; ++r) {
      const int row = wave * 16 + quad * 4 + r;
      __bf16* orow = Opart + ((size_t)chunk * BM + row) * DK + l15;
      #pragma unroll
      for (int dt = 0; dt < 8; ++dt) orow[dt * 16] = (__bf16)o_acc[dt][r];
    }
    if (l15 == 0) {
      #pragma unroll
      for (int r = 0; r < 4; ++r) {
        const int row = wave * 16 + quad * 4 + r;
        stats[((size_t)chunk * BM + row) * 2 + 0] = m_r[r];
        stats[((size_t)chunk * BM + row) * 2 + 1] = l_r[r];
      }
    }
  }
}

// ---- combine: wave per query row, lane covers 2 columns (bf16 partials).
// G==8 specialization: unrolled loop -> 8 independent loads in flight. ----
template <int GF>
__device__ __forceinline__ void reduce_body(const __bf16* __restrict__ Opart,
                                            const float* __restrict__ stats,
                                            float* __restrict__ O, int G) {
  const int wave = threadIdx.x >> 6, lane = threadIdx.x & 63;
  const int row = blockIdx.x * 4 + wave;
  const int qt = row >> 7, r = row & 127;
  const int n = (GF > 0) ? GF : G;

  float M = -INFINITY;
  #pragma unroll
  for (int g = 0; g < n; ++g)
    M = fmaxf(M, stats[((size_t)(qt * n + g) * BM + r) * 2]);

  float L = 0.f, ax = 0.f, ay = 0.f;
  #pragma unroll
  for (int g = 0; g < n; ++g) {
    const size_t sidx = (size_t)(qt * n + g) * BM + r;
    const float m = stats[sidx * 2];
    const float w = (m == -INFINITY) ? 0.f : __expf(m - M);
    L += stats[sidx * 2 + 1] * w;
    bf16x2_t o = *(const bf16x2_t*)&Opart[sidx * DK + lane * 2];
    ax += w * (float)o[0];
    ay += w * (float)o[1];
  }
  const float inv = 1.f / L;
  float2 res; res.x = ax * inv; res.y = ay * inv;
  *(float2*)&O[(size_t)row * DK + lane * 2] = res;
}

__global__ __launch_bounds__(256)
void fa_reduce(const __bf16* __restrict__ Opart, const float* __restrict__ stats,
               float* __restrict__ O, int G) {
  if (G == 8) reduce_body<8>(Opart, stats, O, G);
  else        reduce_body<0>(Opart, stats, O, G);
}

extern "C" void kernel_launch(void* const* d_in, const int* in_sizes, int n_in,
                              void* d_out, int out_size, void* d_ws, size_t ws_size,
                              hipStream_t stream) {
  (void)in_sizes; (void)n_in; (void)out_size;
  const float* q = (const float*)d_in[0];
  const float* k = (const float*)d_in[1];
  const float* v = (const float*)d_in[2];
  float* out = (float*)d_out;

  const size_t conv = 3 * (size_t)S_LEN * DK * 2;                       // 6 MB
  const size_t per_g = (size_t)NQT * BM * DK * 2                        // bf16 Opart
                     + (size_t)NQT * BM * 2 * sizeof(float);            // stats
  int G = 1;
  if (ws_size > conv + 2 * per_g) {
    G = (int)((ws_size - conv) / per_g);
    if (G > 8) G = 8;
  }

  __bf16* Qb = (__bf16*)d_ws;
  __bf16* Kb = Qb + (size_t)S_LEN * DK;
  __bf16* Vt = Kb + (size_t)S_LEN * DK;
  __bf16* Opart = Vt + (size_t)S_LEN * DK;
  float* stats = (float*)(Opart + (size_t)NQT * G * BM * DK);

  prep<<<2176, 256, 0, stream>>>(q, k, v, Qb, Kb, Vt);

  if (G >= 2) {
    fa_part<<<dim3(NQT, G), 512, 0, stream>>>(Qb, Kb, Vt, Opart, nullptr, stats, G, 0);
    fa_reduce<<<S_LEN / 4, 256, 0, stream>>>(Opart, stats, out, G);
  } else {
    fa_part<<<dim3(NQT, 1), 512, 0, stream>>>(Qb, Kb, Vt, Opart, out, stats, 1, 1);
  }
}